// Round 9
// baseline (161.715 us; speedup 1.0000x reference)
//
#include <hip/hip_runtime.h>
#include <stdint.h>

// ---------- types ----------
typedef __bf16 bf16x8 __attribute__((ext_vector_type(8)));
typedef float f32x4 __attribute__((ext_vector_type(4)));
typedef float float4v __attribute__((ext_vector_type(4)));
typedef unsigned short u16x8 __attribute__((ext_vector_type(8)));

// round-to-nearest-even fp32 -> bf16
__device__ __forceinline__ unsigned short f2bf(float f) {
    unsigned u = __float_as_uint(f);
    u += 0x7fffu + ((u >> 16) & 1u);
    return (unsigned short)(u >> 16);
}

// fast stable softplus: max(x,0) + log(1+exp(-|x|))
__device__ __forceinline__ float softplus(float x) {
    return fmaxf(x, 0.0f) + __logf(1.0f + __expf(-fabsf(x)));
}

// async global->LDS, 16B per lane (gfx950). LDS dest must be wave-uniform
// base + lane*16 (lane-ordered, contiguous).
__device__ __forceinline__ void gl_lds16(const void* gptr, void* lptr) {
    auto g = reinterpret_cast<const __attribute__((address_space(1))) void*>(
        reinterpret_cast<uintptr_t>(gptr));
    auto l = reinterpret_cast<__attribute__((address_space(3))) void*>(
        reinterpret_cast<uintptr_t>(lptr));
    __builtin_amdgcn_global_load_lds(g, l, 16, 0, 0);
}

// ---------- fused prep: input f32->bf16  AND  w = mu + softplus(rho)*eps ----
__global__ void prep_kernel(const float* __restrict__ in,
                            const float* __restrict__ mu,
                            const float* __restrict__ rho,
                            const float* __restrict__ eps,
                            unsigned short* __restrict__ in_bf,
                            unsigned short* __restrict__ w_bf,
                            int nIn8, int nW8) {
    int i = blockIdx.x * blockDim.x + threadIdx.x;
    if (i < nIn8) {
        const float4v* p = (const float4v*)in + (size_t)i * 2;
        float4v a = p[0], b = p[1];
        u16x8 r;
        r[0] = f2bf(a[0]); r[1] = f2bf(a[1]); r[2] = f2bf(a[2]); r[3] = f2bf(a[3]);
        r[4] = f2bf(b[0]); r[5] = f2bf(b[1]); r[6] = f2bf(b[2]); r[7] = f2bf(b[3]);
        ((u16x8*)in_bf)[i] = r;
    } else {
        int j = i - nIn8;
        if (j >= nW8) return;
        const float4v* pm = (const float4v*)mu  + (size_t)j * 2;
        const float4v* pr = (const float4v*)rho + (size_t)j * 2;
        const float4v* pe = (const float4v*)eps + (size_t)j * 2;
        float4v m0 = pm[0], m1 = pm[1];
        float4v r0 = pr[0], r1 = pr[1];
        float4v e0 = pe[0], e1 = pe[1];
        u16x8 r;
        r[0] = f2bf(m0[0] + softplus(r0[0]) * e0[0]);
        r[1] = f2bf(m0[1] + softplus(r0[1]) * e0[1]);
        r[2] = f2bf(m0[2] + softplus(r0[2]) * e0[2]);
        r[3] = f2bf(m0[3] + softplus(r0[3]) * e0[3]);
        r[4] = f2bf(m1[0] + softplus(r1[0]) * e1[0]);
        r[5] = f2bf(m1[1] + softplus(r1[1]) * e1[1]);
        r[6] = f2bf(m1[2] + softplus(r1[2]) * e1[2]);
        r[7] = f2bf(m1[3] + softplus(r1[3]) * e1[3]);
        ((u16x8*)w_bf)[j] = r;
    }
}

// ---------- GEMM: C[M,N] = A[M,K] * B[N,K]^T + bias, bf16 in / f32 out -----
// R9: faithful m201-style PHASE PIPELINE at 256x128.
//   R0-R8 established: every 2-phase-per-K-step structure in this family
//   lands at 41-52us / MfmaUtil 26-32% regardless of schedule, occupancy,
//   or LDS traffic (m233: stage+vmcnt+barrier chain dominates 2-phase).
//   This is the m201 combo, adapted:
//   - BM=256 x BN=128 -> grid 16x16 = 256 = 1 block/CU (m201 occupancy
//     point; 8 waves self-overlap, no co-resident block needed).
//   - 8 waves 4Mx2N, each 64x64 out (traffic-minimal: 176KB LDS r+w per
//     K-window vs R0's 256KB). acc[4][4] = 64 VGPR.
//   - K-tile 64 = two 32-halves; 4-slot half-tile ring (A[256][32] 16KB +
//     B[128][32] 8KB = 24KB/slot, 96KB dynamic LDS). slot(d,kh)=d*2+kh.
//   - Per phase: 8 ds_read_b128 (4 A + 4 B frags) ; issue 1 half-tile
//     stage (3 gl_lds) ; lgkmcnt(0) ; setprio(1) 16 MFMA setprio(0) ;
//     s_barrier. Reads and MFMAs of the SAME phase; stage issue overlaps.
//   - ONE vmcnt(3)+barrier per K-tile (covers both its halves; 3 newest
//     loads = next half-tile stay in flight). Never drained to 0.
//   - Slot lifetime: phase A stages (t+1,k1) -> opposite dbuf; phase B
//     stages (t+2,k0) -> the slot phase A finished reading (lgkmcnt(0)+
//     barrier precede). Tail clamps stage tile to nt-1 (dead slots only).
//   - KC=32 XOR swizzle (R4/R6-verified 0 conflicts): slot(row,pkg) holds
//     logical kg = pkg ^ ((row>>1)&3); staged via swizzled GLOBAL source
//     (LDS dest linear), read via quad^((lane16>>1)&3).
#define BM 256
#define BN 128
#define SLOT_U 12288      // ushorts per half-tile slot (24 KB)

__global__ __launch_bounds__(512, 2)
void gemm_bt_kernel(const unsigned short* __restrict__ A,   // [M,K] bf16
                    const unsigned short* __restrict__ B,   // [N,K] bf16
                    const float* __restrict__ bias,         // [N]
                    float* __restrict__ C,                  // [M,N] f32
                    int M, int N, int K) {
    extern __shared__ unsigned short smem[];    // 4 * SLOT_U = 96 KB

    const int t      = threadIdx.x;
    const int lane   = t & 63;
    const int wave   = t >> 6;          // 0..7
    const int lane16 = lane & 15;
    const int quad   = lane >> 4;       // 0..3
    const int wm     = wave & 3;        // wave row: 0..3 (64 rows each)
    const int wn     = wave >> 2;       // wave col: 0..1 (64 cols each)

    const int m0 = blockIdx.y * BM;
    const int n0 = blockIdx.x * BN;

    // ---- staging: half-tile = A[256][32] + B[128][32] = 1536 x 16B chunks,
    // 512 thr -> 2 A-loads + 1 B-load each. LDS dest LINEAR (lane-ordered);
    // global SOURCE k-group carries the swizzle.
    const int rS  = t >> 2;                       // 0..127
    const int key = (t >> 3) & 3;                 // (row>>1)&3, rows rS & rS+128
    const int kgs = ((t & 3) ^ key) * 8;          // swizzled k-elem offset

    const unsigned short* aR0 = A + (size_t)(m0 + rS)       * K + kgs;
    const unsigned short* aR1 = A + (size_t)(m0 + 128 + rS) * K + kgs;
    const unsigned short* bR  = B + (size_t)(n0 + rS)       * K + kgs;

    auto stage = [&](int slot, int k0) {          // k0 in elements
        unsigned short* s = smem + slot * SLOT_U;
        gl_lds16(aR0 + k0, s + t * 8);
        gl_lds16(aR1 + k0, s + 4096 + t * 8);
        gl_lds16(bR  + k0, s + 8192 + t * 8);
    };

    // ---- fragment read offsets (ushort idx in slot), swizzle-matched ----
    const int sw  = (lane16 >> 1) & 3;
    const int pk  = (quad ^ sw) * 8;
    const int oA0 = (wm * 64 + lane16) * 32 + pk;          // + mi*512
    const int oB0 = 8192 + (wn * 64 + lane16) * 32 + pk;   // + ni*512

    f32x4 acc[4][4] = {};

    auto phase = [&](const unsigned short* sl, int stageSlot, int stageK0) {
        bf16x8 af[4], bf[4];
#pragma unroll
        for (int mi = 0; mi < 4; ++mi)
            af[mi] = *(const bf16x8*)(sl + oA0 + mi * 512);
#pragma unroll
        for (int ni = 0; ni < 4; ++ni)
            bf[ni] = *(const bf16x8*)(sl + oB0 + ni * 512);
        stage(stageSlot, stageK0);
        asm volatile("s_waitcnt lgkmcnt(0)" ::: "memory");
        __builtin_amdgcn_sched_barrier(0);
        __builtin_amdgcn_s_setprio(1);
#pragma unroll
        for (int mi = 0; mi < 4; ++mi)
#pragma unroll
            for (int ni = 0; ni < 4; ++ni)
                acc[mi][ni] = __builtin_amdgcn_mfma_f32_16x16x32_bf16(
                    af[mi], bf[ni], acc[mi][ni], 0, 0, 0);
        __builtin_amdgcn_s_setprio(0);
        __builtin_amdgcn_s_barrier();
    };

    const int nt = K / 64;              // 32 K-tiles
    // prologue: (0,k0)->slot0, (0,k1)->slot1, (1,k0)->slot2 ; 9 loads
    stage(0, 0);
    stage(1, 32);
    stage(2, 64);

    for (int tt = 0; tt < nt; ++tt) {
        const int d = tt & 1;
        // gate tile tt: all but the newest half-tile (3 loads) landed
        asm volatile("s_waitcnt vmcnt(3)" ::: "memory");
        __builtin_amdgcn_sched_barrier(0);
        __builtin_amdgcn_s_barrier();
        __builtin_amdgcn_sched_barrier(0);
        // phase A: compute k-half 0; stage (tt+1, k1) into opposite dbuf
        const int sA = ((tt + 1 < nt) ? (tt + 1) : (nt - 1)) * 64 + 32;
        phase(smem + (d * 2) * SLOT_U, (d ^ 1) * 2 + 1, sA);
        // phase B: compute k-half 1; stage (tt+2, k0) into phase-A's slot
        const int sB = ((tt + 2 < nt) ? (tt + 2) : (nt - 1)) * 64;
        phase(smem + (d * 2 + 1) * SLOT_U, d * 2, sB);
    }

    // epilogue: C/D layout col=lane&15, row=quad*4+reg (m89-verified)
    float bv[4];
#pragma unroll
    for (int ni = 0; ni < 4; ++ni)
        bv[ni] = bias[n0 + wn * 64 + ni * 16 + lane16];

#pragma unroll
    for (int mi = 0; mi < 4; ++mi) {
        const int rbase = m0 + wm * 64 + mi * 16 + quad * 4;
#pragma unroll
        for (int ni = 0; ni < 4; ++ni) {
            const int col = n0 + wn * 64 + ni * 16 + lane16;
#pragma unroll
            for (int rr = 0; rr < 4; ++rr)
                C[(size_t)(rbase + rr) * N + col] = acc[mi][ni][rr] + bv[ni];
        }
    }
}

extern "C" void kernel_launch(void* const* d_in, const int* in_sizes, int n_in,
                              void* d_out, int out_size, void* d_ws, size_t ws_size,
                              hipStream_t stream) {
    const float* input = (const float*)d_in[0];
    const float* mu    = (const float*)d_in[1];
    const float* rho   = (const float*)d_in[2];
    const float* eps   = (const float*)d_in[3];
    const float* bias  = (const float*)d_in[4];
    float* out = (float*)d_out;

    const int OUT = in_sizes[4];              // 2048
    const int IN  = in_sizes[1] / OUT;        // 2048
    const int M   = in_sizes[0] / IN;         // 4096

    unsigned short* in_bf = (unsigned short*)d_ws;                 // M*IN bf16
    unsigned short* w_bf  = in_bf + (size_t)M * IN;                // OUT*IN bf16

    // one-time opt-in for 96 KB dynamic LDS (host-side, graph-capture safe)
    static bool attr_done = false;
    if (!attr_done) {
        (void)hipFuncSetAttribute(
            reinterpret_cast<const void*>(&gemm_bt_kernel),
            hipFuncAttributeMaxDynamicSharedMemorySize, 4 * SLOT_U * 2);
        attr_done = true;
    }

    const int nIn8 = (M * IN) / 8;
    const int nW8  = (OUT * IN) / 8;
    prep_kernel<<<dim3((nIn8 + nW8 + 255) / 256), 256, 0, stream>>>(
        input, mu, rho, eps, in_bf, w_bf, nIn8, nW8);

    gemm_bt_kernel<<<dim3(OUT / BN, M / BM), 512, 4 * SLOT_U * 2, stream>>>(
        in_bf, w_bf, bias, out, M, OUT, IN);
}